// Round 7
// baseline (449.946 us; speedup 1.0000x reference)
//
#include <hip/hip_runtime.h>
#include <hip/hip_bf16.h>

typedef int i32x4 __attribute__((ext_vector_type(4)));

#define N_TOKENS 32768
#define N_CODES 4096
#define DIM 1280
#define NT 20            // K-tiles of 64 (i8)

__device__ __forceinline__ void load_lds16(const void* g, void* l) {
    __builtin_amdgcn_global_load_lds(
        (const __attribute__((address_space(1))) unsigned int*)g,
        (__attribute__((address_space(3))) unsigned int*)l,
        16, 0, 0);
}

// ---------------------------------------------------------------------------
// Kernel 0: per-row symmetric int8 quantize (RNE), verified r5/r6.
// FRAG=false: row-major (for E, staged via LDS).
// FRAG=true:  fragment-major (for X): 1024B block per (row-tile rb, k-tile t,
// 16-row group m): byte for (row=16R+lr, k=t*64+g*16+b) at
// ((rb*20+t)*16+m)*1024 + lr*64 + g*16 + b  -> a wave's A-fragment is one
// contiguous 1024B global_load_dwordx4 (lane offset lr*64+g*16).
// ---------------------------------------------------------------------------
template <bool FRAG>
__global__ __launch_bounds__(256) void quantize_i8_kernel(
    const float* __restrict__ src, signed char* __restrict__ dst,
    float* __restrict__ scale, int nrows)
{
    int row = blockIdx.x * 4 + (threadIdx.x >> 6);
    if (row >= nrows) return;
    int lane = threadIdx.x & 63;
    const float4* s4 = (const float4*)(src + (size_t)row * DIM);
    float4 v[5];
    float amax = 0.f;
    #pragma unroll
    for (int j = 0; j < 5; ++j) {
        v[j] = s4[j * 64 + lane];
        amax = fmaxf(amax, fmaxf(fmaxf(fabsf(v[j].x), fabsf(v[j].y)),
                                 fmaxf(fabsf(v[j].z), fabsf(v[j].w))));
    }
    #pragma unroll
    for (int d = 1; d < 64; d <<= 1) amax = fmaxf(amax, __shfl_xor(amax, d));
    amax = fmaxf(amax, 1e-20f);
    float inv = 127.0f / amax;
    #pragma unroll
    for (int j = 0; j < 5; ++j) {
        int q0 = (int)rintf(v[j].x * inv), q1 = (int)rintf(v[j].y * inv);
        int q2 = (int)rintf(v[j].z * inv), q3 = (int)rintf(v[j].w * inv);
        int w = (q0 & 0xFF) | ((q1 & 0xFF) << 8) |
                ((q2 & 0xFF) << 16) | ((q3 & 0xFF) << 24);
        if (FRAG) {
            int c = (j * 64 + lane) << 2;            // byte col 0..1279
            size_t dest = ((size_t)((row >> 8) * 20 + (c >> 6)) << 14)
                        + (((row >> 4) & 15) << 10) + ((row & 15) << 6) + (c & 63);
            *(int*)(dst + dest) = w;
        } else {
            ((int*)(dst + (size_t)row * DIM))[j * 64 + lane] = w;
        }
    }
    if (lane == 0) scale[row] = amax * (1.0f / 127.0f);
}

// ---------------------------------------------------------------------------
// Kernel 1: i8 GEMM 256x256, 16 waves (4x4), BK=64, mfma_i32_16x16x64_i8.
// A: DIRECT global->reg from fragment-major XqF (no LDS). B: LDS-staged
// (E panels are L2-resident per XCD), 4 x 16KB buffers, r6 swizzle.
// Ledger (per-thread VMEM order):  steady entering iter t: [B(t+2), A(t)x4].
//   STAGE_B(t+3)  -> [B(t+2), A(t)x4, B(t+3)] (6)
//   vmcnt(1)      -> only B(t+3) left: A(t) ready; B(t),B(t+1),B(t+2) retired
//   frag ds_reads + MFMA(t)   (lgkm auto; B(t) certified by every wave's
//                              vmcnt(1) two barriers ago)
//   LOAD_A(t+1)   -> [B(t+3), A(t+1)x4] (5)
//   s_barrier; sched_barrier(0)
// Buffer overwrite: STAGE_B(t+3) hits buf (t-1)&3; its reads were consumed
// (lgkm) before the t-1 end barrier => safe.
// ---------------------------------------------------------------------------
__global__ __launch_bounds__(1024, 4) void gemm_argmax_kernel(
    const signed char* __restrict__ XqF, const signed char* __restrict__ Eq,
    const float* __restrict__ sx, const float* __restrict__ se,
    unsigned* __restrict__ pkeys)
{
    __shared__ __align__(16) char lds[4 * 16384];   // 64 KB (B only)

    int bid = blockIdx.x;
    // bijective XCD swizzle; each XCD owns 2 cb0 values x all 128 rb
    int swz = (bid & 7) * 256 + (bid >> 3);
    int cb0 = swz >> 7, rb = swz & 127;
    int row0 = rb << 8, col0 = cb0 << 8;

    int tid = threadIdx.x;
    int wid = tid >> 6, lane = tid & 63;
    int wm = wid >> 2, wn = wid & 3;        // 4x4 wave grid, tile 64x64
    int lr = lane & 15, g = lane >> 4;

    // B fragment offset in 16KB buffer (r6-verified swizzle)
    int slot = (((lr & 1) << 2) + g) ^ ((lr >> 1) & 7);
    int boff = ((wn << 5) + (lr >> 1)) * 128 + slot * 16;

    // A fragment-major base: [rb][t][wm*4+m][1024B] + lane offset
    const signed char* Aptr = XqF + (size_t)rb * (20 * 16384)
                              + (wm << 12) + (lr << 6) + (g << 4);

    i32x4 acc[4][4] = {};
    i32x4 a[4];

    auto STAGE_B = [&](int t) {
        int base = (t & 3) * 16384;
        int f = tid;
        int rp = f >> 3, c = f & 7;
        int cp = c ^ (rp & 7);
        int gr = (rp << 1) + (cp >> 2);
        int kc = (t << 6) + ((cp & 3) << 4);
        load_lds16(Eq + (size_t)(col0 + gr) * DIM + kc, lds + base + (f << 4));
    };
    auto LOAD_A = [&](int t) {
        const signed char* p = Aptr + (size_t)t * 16384;
        #pragma unroll
        for (int m = 0; m < 4; ++m) a[m] = *(const i32x4*)(p + (m << 10));
    };
    auto MFMA_T = [&](int t) {
        const char* pB = lds + (t & 3) * 16384 + boff;
        i32x4 b[4];
        #pragma unroll
        for (int n = 0; n < 4; ++n) b[n] = *(const i32x4*)(pB + (n << 10));
        __builtin_amdgcn_s_setprio(1);
        #pragma unroll
        for (int m = 0; m < 4; ++m)
            #pragma unroll
            for (int n = 0; n < 4; ++n)
                acc[m][n] = __builtin_amdgcn_mfma_i32_16x16x64_i8(
                    a[m], b[n], acc[m][n], 0, 0, 0);
        __builtin_amdgcn_s_setprio(0);
    };

    // prologue: A(0) + B(0..2); vmcnt(2) leaves B(1),B(2) => A(0),B(0) done
    LOAD_A(0);
    STAGE_B(0); STAGE_B(1); STAGE_B(2);
    asm volatile("s_waitcnt vmcnt(2)" ::: "memory");
    __builtin_amdgcn_s_barrier();
    __builtin_amdgcn_sched_barrier(0);

    for (int t = 0; t < NT - 3; ++t) {
        STAGE_B(t + 3);
        asm volatile("s_waitcnt vmcnt(1)" ::: "memory");
        MFMA_T(t);
        LOAD_A(t + 1);
        __builtin_amdgcn_s_barrier();
        __builtin_amdgcn_sched_barrier(0);
    }
    asm volatile("s_waitcnt vmcnt(0)" ::: "memory");
    MFMA_T(NT - 3);
    LOAD_A(NT - 2);
    asm volatile("s_waitcnt vmcnt(0)" ::: "memory");
    __builtin_amdgcn_s_barrier();
    __builtin_amdgcn_sched_barrier(0);
    MFMA_T(NT - 2);
    LOAD_A(NT - 1);
    asm volatile("s_waitcnt vmcnt(0)" ::: "memory");
    __builtin_amdgcn_s_barrier();
    __builtin_amdgcn_sched_barrier(0);
    MFMA_T(NT - 1);
    __syncthreads();   // drain; LDS reused for epilogue merge

    // ---- dequant + fused top-2 argmax epilogue (r6-verified) ----
    // C/D frag layout (dtype-independent): col = lr, row = g*4 + r.
    float se_l[4];
    #pragma unroll
    for (int n = 0; n < 4; ++n)
        se_l[n] = se[col0 + (wn << 6) + (n << 4) + lr];

    uint2* lk2 = (uint2*)lds;   // [256 rows][4 wn]
    #pragma unroll
    for (int m = 0; m < 4; ++m) {
        #pragma unroll
        for (int r = 0; r < 4; ++r) {
            int row = (wm << 6) + (m << 4) + (g << 2) + r;
            float fx = sx[row0 + row];
            unsigned b1 = 0, b2 = 0;
            #pragma unroll
            for (int n = 0; n < 4; ++n) {
                float s = (float)acc[m][n][r] * (fx * se_l[n]);
                int cib = ((wn & 1) << 6) + (n << 4) + lr;   // col in 128-block
                unsigned u = __float_as_uint(s);
                u = (u & 0x80000000u) ? ~u : (u | 0x80000000u);
                unsigned key = (u & 0xFFFFFF80u) | (unsigned)(127 - cib);
                if (key > b1) { b2 = b1; b1 = key; }
                else if (key > b2) b2 = key;
            }
            #pragma unroll
            for (int d = 1; d < 16; d <<= 1) {   // merge across 16 lanes (lr)
                unsigned o1 = __shfl_xor(b1, d), o2 = __shfl_xor(b2, d);
                if (o1 > b1) { b2 = (b1 > o2) ? b1 : o2; b1 = o1; }
                else if (o1 > b2) b2 = o1;
            }
            if (lr == 0) {
                uint2 v; v.x = b1; v.y = b2;
                lk2[(row << 2) + wn] = v;
            }
        }
    }
    __syncthreads();
    if (tid < 512) {
        int row = tid >> 1, h = tid & 1;
        uint2 p0 = lk2[(row << 2) + (h << 1)];
        uint2 p1 = lk2[(row << 2) + (h << 1) + 1];
        unsigned b1 = p0.x, b2 = p0.y;
        if (p1.x > b1) { b2 = (b1 > p1.y) ? b1 : p1.y; b1 = p1.x; }
        else if (p1.x > b2) b2 = p1.x;
        uint2 out; out.x = b1; out.y = b2;
        *(uint2*)&pkeys[((size_t)(row0 + row) << 6) + (((cb0 << 1) + h) << 1)] = out;
    }
}

// ---------------------------------------------------------------------------
// Kernel 2: fused exact fp64 refine + gather + loss partial. One wave/token.
// Threshold 3e-3 (~9 sigma i8 noise). Verified r5/r6.
// ---------------------------------------------------------------------------
__global__ __launch_bounds__(64) void refine_gather_kernel(
    const float* __restrict__ X, const float* __restrict__ E,
    const unsigned* __restrict__ pkeys, float* __restrict__ outq,
    float* __restrict__ outidx, float* __restrict__ sums)
{
    int token = blockIdx.x;
    int lane = threadIdx.x;
    unsigned k = pkeys[((size_t)token << 6) + lane];
    unsigned m = k & 0xFFFFFF80u;
    float s = __uint_as_float((m & 0x80000000u) ? (m & 0x7FFFFFFFu) : ~m);
    float smax = s;
    #pragma unroll
    for (int d = 1; d < 64; d <<= 1) smax = fmaxf(smax, __shfl_xor(smax, d));
    bool cand = s >= smax - 3e-3f;
    unsigned long long ball = __ballot(cand);

    const float4* x4 = (const float4*)(X + (size_t)token * DIM);
    float4 xv[5];
    #pragma unroll
    for (int j = 0; j < 5; ++j) xv[j] = x4[j * 64 + lane];

    double best_s = -1.0e300;
    int best_i = 0x7FFFFFFF;
    while (ball) {
        int src = __ffsll(ball) - 1;
        ball &= ball - 1;
        unsigned ck = __shfl(k, src);
        int cidx = ((src >> 1) << 7) + (127 - (int)(ck & 127u));
        const float4* e4 = (const float4*)(E + (size_t)cidx * DIM);
        double d = 0.0, ee = 0.0;
        #pragma unroll
        for (int j = 0; j < 5; ++j) {
            float4 ev = e4[j * 64 + lane];
            d += (double)xv[j].x * (double)ev.x + (double)xv[j].y * (double)ev.y
               + (double)xv[j].z * (double)ev.z + (double)xv[j].w * (double)ev.w;
            ee += (double)ev.x * (double)ev.x + (double)ev.y * (double)ev.y
                + (double)ev.z * (double)ev.z + (double)ev.w * (double)ev.w;
        }
        #pragma unroll
        for (int dd = 1; dd < 64; dd <<= 1) {
            d += __shfl_xor(d, dd);
            ee += __shfl_xor(ee, dd);
        }
        double sc = 2.0 * d - ee;
        if (sc > best_s || (sc == best_s && cidx < best_i)) { best_s = sc; best_i = cidx; }
    }

    const float4* e4 = (const float4*)(E + (size_t)best_i * DIM);
    float4* o4 = (float4*)(outq + (size_t)token * DIM);
    float local = 0.0f;
    #pragma unroll
    for (int j = 0; j < 5; ++j) {
        float4 q = e4[j * 64 + lane];
        o4[j * 64 + lane] = q;
        float dx = xv[j].x - q.x, dy = xv[j].y - q.y;
        float dz = xv[j].z - q.z, dw = xv[j].w - q.w;
        local += dx * dx + dy * dy + dz * dz + dw * dw;
    }
    #pragma unroll
    for (int d = 1; d < 64; d <<= 1) local += __shfl_xor(local, d);
    if (lane == 0) {
        sums[token] = local;
        outidx[token] = (float)best_i;
    }
}

// ---------------------------------------------------------------------------
// Kernel 3: deterministic final loss reduction (fixed tree).
// ---------------------------------------------------------------------------
__global__ __launch_bounds__(256) void loss_kernel(
    const float* __restrict__ sums, float* __restrict__ out_loss)
{
    __shared__ double red[256];
    int t = threadIdx.x;
    double s = 0.0;
    for (int i = t; i < N_TOKENS; i += 256) s += (double)sums[i];
    red[t] = s;
    __syncthreads();
    for (int off = 128; off > 0; off >>= 1) {
        if (t < off) red[t] += red[t + off];
        __syncthreads();
    }
    if (t == 0) out_loss[0] = (float)(red[0] / (double)((size_t)N_TOKENS * DIM));
}

extern "C" void kernel_launch(void* const* d_in, const int* in_sizes, int n_in,
                              void* d_out, int out_size, void* d_ws, size_t ws_size,
                              hipStream_t stream)
{
    const float* X = (const float*)d_in[0];   // (32768, 1280) fp32
    const float* E = (const float*)d_in[1];   // (4096, 1280) fp32

    float* outq = (float*)d_out;                       // (32768,1280)
    float* outidx = outq + (size_t)N_TOKENS * DIM;     // (32768,) as float
    float* outloss = outidx + N_TOKENS;                // scalar

    // i8 temps + scales inside outq region (47.3 MB of 167.9 MB); consumed
    // by GEMM, then fully overwritten by refine_gather in-stream.
    signed char* XqF = (signed char*)d_out;                       // 41.9 MB frag-major
    signed char* Eq = XqF + (size_t)N_TOKENS * DIM;               // 5.2 MB row-major
    float* sxs = (float*)(Eq + (size_t)N_CODES * DIM);            // 128 KB
    float* ses = sxs + N_TOKENS;                                  // 16 KB

    unsigned* pkeys = (unsigned*)d_ws;                            // 8 MB
    float* sums = (float*)((char*)d_ws + (size_t)N_TOKENS * 64 * sizeof(unsigned));

    quantize_i8_kernel<true><<<dim3(N_TOKENS / 4), dim3(256), 0, stream>>>(X, XqF, sxs, N_TOKENS);
    quantize_i8_kernel<false><<<dim3(N_CODES / 4), dim3(256), 0, stream>>>(E, Eq, ses, N_CODES);
    gemm_argmax_kernel<<<dim3(2048), dim3(1024), 0, stream>>>(XqF, Eq, sxs, ses, pkeys);
    refine_gather_kernel<<<dim3(N_TOKENS), dim3(64), 0, stream>>>(X, E, pkeys, outq, outidx, sums);
    loss_kernel<<<dim3(1), dim3(256), 0, stream>>>(sums, outloss);
}

// Round 8
// 380.457 us; speedup vs baseline: 1.1826x; 1.1826x over previous
//
#include <hip/hip_runtime.h>
#include <hip/hip_bf16.h>

typedef int i32x4 __attribute__((ext_vector_type(4)));

#define N_TOKENS 32768
#define N_CODES 4096
#define DIM 1280
#define NT 20            // K-tiles of 64 (i8)
#define BUFSZ 24576      // A 8KB + B 16KB per K-tile buffer
#define NBUF 3

__device__ __forceinline__ void load_lds16(const void* g, void* l) {
    __builtin_amdgcn_global_load_lds(
        (const __attribute__((address_space(1))) unsigned int*)g,
        (__attribute__((address_space(3))) unsigned int*)l,
        16, 0, 0);
}

// ---------------------------------------------------------------------------
// Kernel 0: per-row symmetric int8 quantize (RNE), row-major, X and E fused
// in one launch (rows 0..N_TOKENS-1 -> Xq/sxs, rest -> Eq/ses). Verified
// numerics (r5/r6): exact-int dot => score err sigma ~3.4e-4, zero-mean;
// refine threshold 3e-3 ~ 9 sigma.
// ---------------------------------------------------------------------------
__global__ __launch_bounds__(256) void quantize_i8_kernel(
    const float* __restrict__ X, const float* __restrict__ E,
    signed char* __restrict__ Xq, signed char* __restrict__ Eq,
    float* __restrict__ sxs, float* __restrict__ ses)
{
    int row = blockIdx.x * 4 + (threadIdx.x >> 6);
    const float* src;
    signed char* dst;
    float* scale;
    if (row < N_TOKENS) {
        src = X + (size_t)row * DIM; dst = Xq + (size_t)row * DIM; scale = sxs + row;
    } else {
        int r = row - N_TOKENS;
        if (r >= N_CODES) return;
        src = E + (size_t)r * DIM; dst = Eq + (size_t)r * DIM; scale = ses + r;
    }
    int lane = threadIdx.x & 63;
    const float4* s4 = (const float4*)src;
    float4 v[5];
    float amax = 0.f;
    #pragma unroll
    for (int j = 0; j < 5; ++j) {
        v[j] = s4[j * 64 + lane];
        amax = fmaxf(amax, fmaxf(fmaxf(fabsf(v[j].x), fabsf(v[j].y)),
                                 fmaxf(fabsf(v[j].z), fabsf(v[j].w))));
    }
    #pragma unroll
    for (int d = 1; d < 64; d <<= 1) amax = fmaxf(amax, __shfl_xor(amax, d));
    amax = fmaxf(amax, 1e-20f);
    float inv = 127.0f / amax;
    int* d4 = (int*)dst;
    #pragma unroll
    for (int j = 0; j < 5; ++j) {
        int q0 = (int)rintf(v[j].x * inv), q1 = (int)rintf(v[j].y * inv);
        int q2 = (int)rintf(v[j].z * inv), q3 = (int)rintf(v[j].w * inv);
        d4[j * 64 + lane] = (q0 & 0xFF) | ((q1 & 0xFF) << 8) |
                            ((q2 & 0xFF) << 16) | ((q3 & 0xFF) << 24);
    }
    if (lane == 0) *scale = amax * (1.0f / 127.0f);
}

// ---------------------------------------------------------------------------
// Kernel 1: i8 GEMM, tile 128x256, 8 waves (2m x 4n, wave tile 64x64),
// BK=64, mfma_i32_16x16x64_i8. 3 LDS buffers x 24KB = 72KB => 2 blocks/CU
// (the r6->r8 lever: independent block barriers let one block's MFMA overlap
// the other's stage/barrier wait; r6 at 1 block/CU measured ~3500 cyc/iter
// vs 1920 LDS-floor).
// Ledger (3 loads/thread/STAGE): prologue STAGE(0),STAGE(1) [6 outst],
// vmcnt(3) => S(0) done, barrier. Iter t: STAGE(t+2) [6 outst]; COMPUTE(t)
// (S(t) certified last iter); vmcnt(3) => S(t+1) done; barrier.
// Overwrite: STAGE(t+2) writes buf (t+2)%3 == (t-1)%3, whose ds_reads
// completed before iter t-1's end barrier => safe. Tail: after loop,
// COMPUTE(NT-2); vmcnt(0); barrier; COMPUTE(NT-1).
// LDS layout per buffer: A 8KB (64 pair-rows x 128B) | B 16KB (128 pair-rows).
// Pair rp holds token-rows {2rp, 2rp+1}; 16B chunk c stores source chunk
// c^(rp&7) (both-sides swizzle, r4-r6 verified).
// ---------------------------------------------------------------------------
__global__ __launch_bounds__(512, 4) void gemm_argmax_kernel(
    const signed char* __restrict__ Xq, const signed char* __restrict__ Eq,
    const float* __restrict__ sx, const float* __restrict__ se,
    unsigned* __restrict__ pkeys)
{
    __shared__ __align__(16) char lds[NBUF * BUFSZ];   // 72 KB

    int bid = blockIdx.x;
    // bijective XCD swizzle: 4096 blocks, 512/XCD, rb-fastest (cb panel hot)
    int swz = (bid & 7) * 512 + (bid >> 3);
    int cb = swz >> 8, rb = swz & 255;        // cb 0..15, rb 0..255
    int row0 = rb << 7, col0 = cb << 8;

    int tid = threadIdx.x;
    int wid = tid >> 6, lane = tid & 63;
    int wm = wid >> 2, wn = wid & 3;          // 2x4 wave grid, tile 64x64
    int lr = lane & 15, g = lane >> 4;

    // per-lane swizzled fragment offsets (row bases multiples of 16 =>
    // rp&7 == (lr>>1)&7)
    int slot = (((lr & 1) << 2) + g) ^ ((lr >> 1) & 7);
    int aoff = ((wm << 5) + (lr >> 1)) * 128 + slot * 16;           // A: 0..8K
    int boff = 8192 + ((wn << 5) + (lr >> 1)) * 128 + slot * 16;    // B: 8K..24K

    i32x4 acc[4][4] = {};

    auto STAGE = [&](int t) {
        int base = (t % NBUF) * BUFSZ;
        int k0 = t << 6;                      // byte k-offset (i8)
        {   // A: 512 slots, 1 per thread
            int rp = tid >> 3, c = tid & 7;
            int cp = c ^ (rp & 7);
            int gr = (rp << 1) + (cp >> 2);
            int kc = k0 + ((cp & 3) << 4);
            load_lds16(Xq + (size_t)(row0 + gr) * DIM + kc, lds + base + (tid << 4));
        }
        #pragma unroll
        for (int i = 0; i < 2; ++i) {         // B: 1024 slots, 2 per thread
            int f = tid + (i << 9);
            int rp = f >> 3, c = f & 7;
            int cp = c ^ (rp & 7);
            int gr = (rp << 1) + (cp >> 2);
            int kc = k0 + ((cp & 3) << 4);
            load_lds16(Eq + (size_t)(col0 + gr) * DIM + kc, lds + base + 8192 + (f << 4));
        }
    };

    auto COMPUTE = [&](int t) {
        int base = (t % NBUF) * BUFSZ;
        const char* pA = lds + base + aoff;
        const char* pB = lds + base + boff;
        i32x4 a[4], b[4];
        #pragma unroll
        for (int m = 0; m < 4; ++m) a[m] = *(const i32x4*)(pA + (m << 10));
        #pragma unroll
        for (int n = 0; n < 4; ++n) b[n] = *(const i32x4*)(pB + (n << 10));
        __builtin_amdgcn_s_setprio(1);
        #pragma unroll
        for (int m = 0; m < 4; ++m)
            #pragma unroll
            for (int n = 0; n < 4; ++n)
                acc[m][n] = __builtin_amdgcn_mfma_i32_16x16x64_i8(
                    a[m], b[n], acc[m][n], 0, 0, 0);
        __builtin_amdgcn_s_setprio(0);
    };

    STAGE(0); STAGE(1);                       // 6 outstanding
    asm volatile("s_waitcnt vmcnt(3)" ::: "memory");
    __builtin_amdgcn_s_barrier();
    __builtin_amdgcn_sched_barrier(0);

    for (int t = 0; t < NT - 2; ++t) {
        STAGE(t + 2);
        COMPUTE(t);
        asm volatile("s_waitcnt vmcnt(3)" ::: "memory");
        __builtin_amdgcn_s_barrier();
        __builtin_amdgcn_sched_barrier(0);
    }
    COMPUTE(NT - 2);
    asm volatile("s_waitcnt vmcnt(0)" ::: "memory");
    __builtin_amdgcn_s_barrier();
    __builtin_amdgcn_sched_barrier(0);
    COMPUTE(NT - 1);
    __syncthreads();   // drain; LDS reused for epilogue merge

    // ---- dequant + fused top-2 argmax epilogue (r6-verified logic) ----
    // C/D frag layout (dtype-independent): col = lr, row = g*4 + r.
    float se_l[4];
    #pragma unroll
    for (int n = 0; n < 4; ++n)
        se_l[n] = se[col0 + (wn << 6) + (n << 4) + lr];

    uint2* lk2 = (uint2*)lds;   // [128 rows][4 wn]
    #pragma unroll
    for (int m = 0; m < 4; ++m) {
        #pragma unroll
        for (int r = 0; r < 4; ++r) {
            int row = (wm << 6) + (m << 4) + (g << 2) + r;   // 0..127
            float fx = sx[row0 + row];
            unsigned b1 = 0, b2 = 0;
            #pragma unroll
            for (int n = 0; n < 4; ++n) {
                float s = (float)acc[m][n][r] * (fx * se_l[n]);
                int cib = ((wn & 1) << 6) + (n << 4) + lr;   // col in 128-block
                unsigned u = __float_as_uint(s);
                u = (u & 0x80000000u) ? ~u : (u | 0x80000000u);
                unsigned key = (u & 0xFFFFFF80u) | (unsigned)(127 - cib);
                if (key > b1) { b2 = b1; b1 = key; }
                else if (key > b2) b2 = key;
            }
            #pragma unroll
            for (int d = 1; d < 16; d <<= 1) {   // merge across 16 lanes (lr)
                unsigned o1 = __shfl_xor(b1, d), o2 = __shfl_xor(b2, d);
                if (o1 > b1) { b2 = (b1 > o2) ? b1 : o2; b1 = o1; }
                else if (o1 > b2) b2 = o1;
            }
            if (lr == 0) {
                uint2 v; v.x = b1; v.y = b2;
                lk2[(row << 2) + wn] = v;
            }
        }
    }
    __syncthreads();
    if (tid < 256) {
        // wn {0,1} -> 128-col-block h=0 of this tile; wn {2,3} -> h=1
        int row = tid >> 1, h = tid & 1;
        uint2 p0 = lk2[(row << 2) + (h << 1)];
        uint2 p1 = lk2[(row << 2) + (h << 1) + 1];
        unsigned b1 = p0.x, b2 = p0.y;
        if (p1.x > b1) { b2 = (b1 > p1.y) ? b1 : p1.y; b1 = p1.x; }
        else if (p1.x > b2) b2 = p1.x;
        uint2 out; out.x = b1; out.y = b2;
        *(uint2*)&pkeys[((size_t)(row0 + row) << 6) + (((cb << 1) + h) << 1)] = out;
    }
}

// ---------------------------------------------------------------------------
// Kernel 2: fused exact fp64 refine + gather + loss partial. One wave/token.
// Threshold 3e-3 (~9 sigma i8 noise). Verified r5-r7.
// ---------------------------------------------------------------------------
__global__ __launch_bounds__(64) void refine_gather_kernel(
    const float* __restrict__ X, const float* __restrict__ E,
    const unsigned* __restrict__ pkeys, float* __restrict__ outq,
    float* __restrict__ outidx, float* __restrict__ sums)
{
    int token = blockIdx.x;
    int lane = threadIdx.x;
    unsigned k = pkeys[((size_t)token << 6) + lane];
    unsigned m = k & 0xFFFFFF80u;
    float s = __uint_as_float((m & 0x80000000u) ? (m & 0x7FFFFFFFu) : ~m);
    float smax = s;
    #pragma unroll
    for (int d = 1; d < 64; d <<= 1) smax = fmaxf(smax, __shfl_xor(smax, d));
    bool cand = s >= smax - 3e-3f;
    unsigned long long ball = __ballot(cand);

    const float4* x4 = (const float4*)(X + (size_t)token * DIM);
    float4 xv[5];
    #pragma unroll
    for (int j = 0; j < 5; ++j) xv[j] = x4[j * 64 + lane];

    double best_s = -1.0e300;
    int best_i = 0x7FFFFFFF;
    while (ball) {
        int src = __ffsll(ball) - 1;
        ball &= ball - 1;
        unsigned ck = __shfl(k, src);
        int cidx = ((src >> 1) << 7) + (127 - (int)(ck & 127u));
        const float4* e4 = (const float4*)(E + (size_t)cidx * DIM);
        double d = 0.0, ee = 0.0;
        #pragma unroll
        for (int j = 0; j < 5; ++j) {
            float4 ev = e4[j * 64 + lane];
            d += (double)xv[j].x * (double)ev.x + (double)xv[j].y * (double)ev.y
               + (double)xv[j].z * (double)ev.z + (double)xv[j].w * (double)ev.w;
            ee += (double)ev.x * (double)ev.x + (double)ev.y * (double)ev.y
                + (double)ev.z * (double)ev.z + (double)ev.w * (double)ev.w;
        }
        #pragma unroll
        for (int dd = 1; dd < 64; dd <<= 1) {
            d += __shfl_xor(d, dd);
            ee += __shfl_xor(ee, dd);
        }
        double sc = 2.0 * d - ee;
        if (sc > best_s || (sc == best_s && cidx < best_i)) { best_s = sc; best_i = cidx; }
    }

    const float4* e4 = (const float4*)(E + (size_t)best_i * DIM);
    float4* o4 = (float4*)(outq + (size_t)token * DIM);
    float local = 0.0f;
    #pragma unroll
    for (int j = 0; j < 5; ++j) {
        float4 q = e4[j * 64 + lane];
        o4[j * 64 + lane] = q;
        float dx = xv[j].x - q.x, dy = xv[j].y - q.y;
        float dz = xv[j].z - q.z, dw = xv[j].w - q.w;
        local += dx * dx + dy * dy + dz * dz + dw * dw;
    }
    #pragma unroll
    for (int d = 1; d < 64; d <<= 1) local += __shfl_xor(local, d);
    if (lane == 0) {
        sums[token] = local;
        outidx[token] = (float)best_i;
    }
}

// ---------------------------------------------------------------------------
// Kernel 3: deterministic final loss reduction (fixed tree).
// ---------------------------------------------------------------------------
__global__ __launch_bounds__(256) void loss_kernel(
    const float* __restrict__ sums, float* __restrict__ out_loss)
{
    __shared__ double red[256];
    int t = threadIdx.x;
    double s = 0.0;
    for (int i = t; i < N_TOKENS; i += 256) s += (double)sums[i];
    red[t] = s;
    __syncthreads();
    for (int off = 128; off > 0; off >>= 1) {
        if (t < off) red[t] += red[t + off];
        __syncthreads();
    }
    if (t == 0) out_loss[0] = (float)(red[0] / (double)((size_t)N_TOKENS * DIM));
}

extern "C" void kernel_launch(void* const* d_in, const int* in_sizes, int n_in,
                              void* d_out, int out_size, void* d_ws, size_t ws_size,
                              hipStream_t stream)
{
    const float* X = (const float*)d_in[0];   // (32768, 1280) fp32
    const float* E = (const float*)d_in[1];   // (4096, 1280) fp32

    float* outq = (float*)d_out;                       // (32768,1280)
    float* outidx = outq + (size_t)N_TOKENS * DIM;     // (32768,) as float
    float* outloss = outidx + N_TOKENS;                // scalar

    // i8 temps + scales inside outq region (47.3 MB of 167.9 MB); consumed
    // by GEMM, then fully overwritten by refine_gather in-stream.
    signed char* Xq = (signed char*)d_out;                        // 41.9 MB
    signed char* Eq = Xq + (size_t)N_TOKENS * DIM;                // 5.2 MB
    float* sxs = (float*)(Eq + (size_t)N_CODES * DIM);            // 128 KB
    float* ses = sxs + N_TOKENS;                                  // 16 KB

    unsigned* pkeys = (unsigned*)d_ws;                            // 8 MB
    float* sums = (float*)((char*)d_ws + (size_t)N_TOKENS * 64 * sizeof(unsigned));

    quantize_i8_kernel<<<dim3((N_TOKENS + N_CODES) / 4), dim3(256), 0, stream>>>(
        X, E, Xq, Eq, sxs, ses);
    gemm_argmax_kernel<<<dim3(4096), dim3(512), 0, stream>>>(Xq, Eq, sxs, ses, pkeys);
    refine_gather_kernel<<<dim3(N_TOKENS), dim3(64), 0, stream>>>(X, E, pkeys, outq, outidx, sums);
    loss_kernel<<<dim3(1), dim3(256), 0, stream>>>(sums, outloss);
}